// Round 7
// baseline (182.850 us; speedup 1.0000x reference)
//
#include <hip/hip_runtime.h>

typedef unsigned short u16;
typedef unsigned int   u32;

#define B_ 2
#define C_ 128
#define T_ 512
#define F_ 64
#define H_ 32
#define D_ 32

// ---- d_out scratch (float offsets): xm1/xf1 fp32 intermediates live in d_out ----
#define XM1_OUT 0u
#define XF1_OUT 2097152u

// ---- d_ws layout (float offsets) ----
#define CORR_OFF 0u          // padded corr: [b][h][518][34]; halo handled in k3 stager
#define WQ_OFF   1127168u    // softmax weights [b][512][32]

// ---------------- K1: projections xm1 = W^T@X + b ----------------
// R11: TLP experiment. Four ILP structures (R0 strided, R5 LDS-dbuf, R7
// DS-only, R10 VGPR-ring) all pinned at ~35us -- ILP falsified. The one
// never-varied axis: occupancy (always 2 blocks/CU = 8 waves/CU, Occ 19%).
// Now: 1024-thread blocks, c-split 4-way (group g does c in [32g,32g+32)),
// 4-deep VGPR ring per group, W broadcast from LDS (16KB), then LDS tree
// reduce (g2,g3 -> g0,g1; g1 -> g0; g0 writes +bias). 16 waves/CU (2x).
// Same 1KB burst shape, same FMA tile (4m x 8h) as R10.
__global__ __launch_bounds__(1024, 4) void k1_proj(const float* __restrict__ xm, const float* __restrict__ xf,
                                                   const float* __restrict__ w1, const float* __restrict__ b1,
                                                   const float* __restrict__ w2, const float* __restrict__ b2,
                                                   float* __restrict__ xm1, float* __restrict__ xf1){
  int blk  = blockIdx.x;
  int mblk = blk & 127;
  int bt   = blk >> 7;           // 0..3
  int b    = bt >> 1, sel = bt & 1;
  int m0   = mblk * 256;
  int tid  = threadIdx.x;
  int g    = tid >> 8;           // c-group 0..3
  int s    = tid & 255;          // 256-thread sub-block, same layout as R10
  int mg   = s & 63;             // m sub-tile: 4 consecutive floats
  int hg   = s >> 6;             // h sub-tile: 8 consecutive h

  const float* X    = (sel ? xf : xm) + (size_t)b * (C_*T_*F_) + m0;
  const float* W    = sel ? w2 : w1;
  const float* bias = sel ? b2 : b1;

  __shared__ float wls[C_*H_];          // 16 KB: full W [c][h]
  __shared__ float red[2][256][36];     // 73.7 KB reduce buffer (+4 pad vs bank 32)

  // Stage W: 4096 floats, 1 float4 per thread.
  *(float4*)(wls + tid*4) = *(const float4*)(W + tid*4);

  const float* Xm = X + (size_t)(32*g) * (T_*F_) + (mg << 2);

  float4 acc[8];
#pragma unroll
  for (int j = 0; j < 8; j++) acc[j] = make_float4(0.f,0.f,0.f,0.f);

  // 4-deep prefetch ring (static indices after full unroll)
  float4 buf[4];
#pragma unroll
  for (int i = 0; i < 4; i++)
    buf[i] = *(const float4*)(Xm + (size_t)i * (T_*F_));

  __syncthreads();               // W staged

#define FMA4(A, Wv) do { \
    A.x = fmaf((Wv), xv.x, A.x); A.y = fmaf((Wv), xv.y, A.y); \
    A.z = fmaf((Wv), xv.z, A.z); A.w = fmaf((Wv), xv.w, A.w); } while (0)

#pragma unroll
  for (int k = 0; k < 32; k++){
    float4 xv = buf[k & 3];
    if (k < 28)
      buf[k & 3] = *(const float4*)(Xm + (size_t)(k + 4) * (T_*F_));
    const float* wk = wls + (32*g + k)*H_ + hg*8;
    float4 wa = *(const float4*)(wk);
    float4 wb = *(const float4*)(wk + 4);
    FMA4(acc[0], wa.x); FMA4(acc[1], wa.y); FMA4(acc[2], wa.z); FMA4(acc[3], wa.w);
    FMA4(acc[4], wb.x); FMA4(acc[5], wb.y); FMA4(acc[6], wb.z); FMA4(acc[7], wb.w);
  }
#undef FMA4

  // ---- tree reduce over c-groups ----
  if (g >= 2){
    float* r = &red[g-2][s][0];
#pragma unroll
    for (int j = 0; j < 8; j++) *(float4*)(r + j*4) = acc[j];
  }
  __syncthreads();
  if (g < 2){
    const float* r = &red[g][s][0];
#pragma unroll
    for (int j = 0; j < 8; j++){
      float4 v = *(const float4*)(r + j*4);
      acc[j].x += v.x; acc[j].y += v.y; acc[j].z += v.z; acc[j].w += v.w;
    }
  }
  __syncthreads();
  if (g == 1){
    float* r = &red[0][s][0];
#pragma unroll
    for (int j = 0; j < 8; j++) *(float4*)(r + j*4) = acc[j];
  }
  __syncthreads();
  if (g == 0){
    const float* r = &red[0][s][0];
#pragma unroll
    for (int j = 0; j < 8; j++){
      float4 v = *(const float4*)(r + j*4);
      acc[j].x += v.x; acc[j].y += v.y; acc[j].z += v.z; acc[j].w += v.w;
    }
    float* O = (sel ? xf1 : xm1) + (size_t)b * (H_*T_*F_) + m0 + (mg << 2);
#pragma unroll
    for (int j = 0; j < 8; j++){
      int h = hg*8 + j;
      float bv = bias[h];
      float4 o = make_float4(acc[j].x + bv, acc[j].y + bv, acc[j].z + bv, acc[j].w + bv);
      *(float4*)(O + (size_t)h * (T_*F_)) = o;
    }
  }
}

// ---------------- K2: corr[b,h,t,d] = sum_f xm1[b,h,t,f] * xf1[b,h,t+d-31,f] ----------------
// R7: XOR-swizzle Bl (kept). Rows differing by 8 at stride 68 floats hit the
// same bank; swizzle float4 slot by ((r>>3)&7)<<2, same on write+read.
#define BSW(r) ((((r) >> 3) & 7) << 2)

__global__ __launch_bounds__(256) void k2_corr(const float* __restrict__ xm1, const float* __restrict__ xf1,
                                               float* __restrict__ corr_pad){
  int blk = blockIdx.x;
  int tt = blk & 7, h = (blk >> 3) & 31, b = blk >> 8;
  int t0 = tt * 64;
  const float* A  = xm1 + ((size_t)(b*H_ + h)) * (T_*F_);
  const float* Bm = xf1 + ((size_t)(b*H_ + h)) * (T_*F_);

  __shared__ float Al[64*68];
  __shared__ float Bl[95*68];
  int tid = threadIdx.x;

  for (int idx = tid; idx < 64*16; idx += 256){
    int r = idx >> 4, q = idx & 15;
    *(float4*)(Al + r*68 + q*4) = *(const float4*)(A + (size_t)(t0 + r)*F_ + q*4);
  }
  for (int idx = tid; idx < 95*16; idx += 256){
    int r = idx >> 4, q = idx & 15;
    int gr = t0 - 31 + r;
    float4 v = make_float4(0.f,0.f,0.f,0.f);
    if (gr >= 0) v = *(const float4*)(Bm + (size_t)gr*F_ + q*4);
    *(float4*)(Bl + r*68 + ((q*4) ^ BSW(r))) = v;
  }
  __syncthreads();

  int tl = tid >> 2, dg = tid & 3;
  float acc[8];
#pragma unroll
  for (int j = 0; j < 8; j++) acc[j] = 0.f;

  for (int fq = 0; fq < 16; fq++){
    float4 a = *(const float4*)(Al + tl*68 + fq*4);
#pragma unroll
    for (int j = 0; j < 8; j++){
      int rbj = tl + dg*8 + j;
      float4 bv = *(const float4*)(Bl + rbj*68 + ((fq*4) ^ BSW(rbj)));
      acc[j] += a.x*bv.x + a.y*bv.y + a.z*bv.z + a.w*bv.w;
    }
  }
  float* o = corr_pad + ((size_t)(b*H_ + h))*(518*34) + (size_t)(t0 + tl + 3)*34 + (dg*8 + 1);
#pragma unroll
  for (int j = 0; j < 8; j++) o[j] = acc[j];
}

// ---------------- K3: 5x3 conv over (t,d) summing h + bc, causal mask, softmax over d ----------------
__global__ __launch_bounds__(256) void k3_conv_softmax(const float* __restrict__ corr_pad,
                                                       const float* __restrict__ wc, const float* __restrict__ bc,
                                                       float* __restrict__ wq){
  int b  = blockIdx.x >> 6;
  int t0 = (blockIdx.x & 63) * 8;
  int tid = threadIdx.x;

  __shared__ float ls[32*12*34];   // [h][12 rows t0..t0+11][34 d]
  const float* cp = corr_pad + (size_t)b * (H_*518*34);
  for (int idx = tid; idx < 32*12*34; idx += 256){
    int h = idx / 408, rem = idx - h*408;
    int r = rem / 34, dd = rem - r*34;
    int gr = t0 + r;
    bool halo = (gr < 3) | (gr > 514) | (dd == 0) | (dd == 33);
    ls[idx] = halo ? 0.f : cp[(size_t)h*(518*34) + (size_t)gr*34 + dd];
  }
  __syncthreads();

  int tl = tid >> 5, d = tid & 31;
  int t = t0 + tl;

  float val = bc[0];
  for (int h = 0; h < H_; h++){
    const float* base = ls + h*408 + tl*34 + d;
    const float* wch = wc + h*15;
#pragma unroll
    for (int kh = 0; kh < 5; kh++){
#pragma unroll
      for (int kw = 0; kw < 3; kw++){
        val += base[kh*34 + kw] * wch[kh*3 + kw];
      }
    }
  }
  if (t + d < D_ - 1) val = -1e13f;

  float m = val;
#pragma unroll
  for (int off = 16; off > 0; off >>= 1) m = fmaxf(m, __shfl_xor(m, off));
  float e = __expf(val - m);
  float s = e;
#pragma unroll
  for (int off = 16; off > 0; off >>= 1) s += __shfl_xor(s, off);

  wq[((size_t)b*T_ + t)*D_ + d] = e / s;
}

// ---------------- K4: out[b,c,t,f] = sum_d w[b,t,d] * xf[b,c,t+d-31,f] ----------------
__global__ __launch_bounds__(256) void k4_out(const float* __restrict__ xf, const float* __restrict__ wq,
                                              float* __restrict__ out){
  int blk = blockIdx.x;
  int tt = blk & 7, c = (blk >> 3) & 127, b = blk >> 10;
  int t0 = tt * 64;
  const float* Xf = xf + ((size_t)(b*C_ + c)) * (T_*F_);

  __shared__ float xfl[95*68];
  __shared__ float wl[64*33];
  int tid = threadIdx.x;

  for (int idx = tid; idx < 95*16; idx += 256){
    int r = idx >> 4, q = idx & 15;
    int gr = t0 - 31 + r;
    float4 v = make_float4(0.f,0.f,0.f,0.f);
    if (gr >= 0) v = *(const float4*)(Xf + (size_t)gr*F_ + q*4);
    *(float4*)(xfl + r*68 + q*4) = v;
  }
  for (int idx = tid; idx < 64*8; idx += 256){
    int r = idx >> 3, q = idx & 7;
    float4 v = *(const float4*)(wq + ((size_t)b*T_ + t0 + r)*D_ + q*4);
    wl[r*33 + q*4 + 0] = v.x; wl[r*33 + q*4 + 1] = v.y;
    wl[r*33 + q*4 + 2] = v.z; wl[r*33 + q*4 + 3] = v.w;
  }
  __syncthreads();

  int tg = tid >> 4, q = tid & 15;
  float4 acc[4];
#pragma unroll
  for (int j = 0; j < 4; j++) acc[j] = make_float4(0.f,0.f,0.f,0.f);

#pragma unroll
  for (int rr = 0; rr < 35; rr++){
    float4 xv = *(const float4*)(xfl + (tg*4 + rr)*68 + q*4);
#pragma unroll
    for (int j = 0; j < 4; j++){
      int d = rr - j;
      if (d >= 0 && d < D_){
        float wv = wl[(tg*4 + j)*33 + d];
        acc[j].x += wv * xv.x; acc[j].y += wv * xv.y;
        acc[j].z += wv * xv.z; acc[j].w += wv * xv.w;
      }
    }
  }
#pragma unroll
  for (int j = 0; j < 4; j++){
    int t = t0 + tg*4 + j;
    float* O = out + (((size_t)(b*C_ + c))*T_ + t)*F_ + q*4;
    *(float4*)O = acc[j];
  }
}

extern "C" void kernel_launch(void* const* d_in, const int* in_sizes, int n_in,
                              void* d_out, int out_size, void* d_ws, size_t ws_size,
                              hipStream_t stream) {
  const float* xm = (const float*)d_in[0];
  const float* xf = (const float*)d_in[1];
  const float* w1 = (const float*)d_in[2];
  const float* b1 = (const float*)d_in[3];
  const float* w2 = (const float*)d_in[4];
  const float* b2 = (const float*)d_in[5];
  const float* wc = (const float*)d_in[6];
  const float* bc = (const float*)d_in[7];
  float* ws = (float*)d_ws;

  float* xm1 = (float*)d_out + XM1_OUT;
  float* xf1 = (float*)d_out + XF1_OUT;

  hipLaunchKernelGGL(k1_proj, dim3(512), dim3(1024), 0, stream, xm, xf, w1, b1, w2, b2, xm1, xf1);
  hipLaunchKernelGGL(k2_corr, dim3(512), dim3(256), 0, stream, xm1, xf1, ws + CORR_OFF);
  hipLaunchKernelGGL(k3_conv_softmax, dim3(128), dim3(256), 0, stream, ws + CORR_OFF, wc, bc, ws + WQ_OFF);
  hipLaunchKernelGGL(k4_out, dim3(2048), dim3(256), 0, stream, xf, ws + WQ_OFF, (float*)d_out);
}

// Round 8
// 177.130 us; speedup vs baseline: 1.0323x; 1.0323x over previous
//
#include <hip/hip_runtime.h>

typedef unsigned short u16;
typedef unsigned int   u32;

#define B_ 2
#define C_ 128
#define T_ 512
#define F_ 64
#define H_ 32
#define D_ 32

// ---- d_out scratch (float offsets): xm1/xf1 fp32 intermediates live in d_out ----
#define XM1_OUT 0u
#define XF1_OUT 2097152u

// ---- d_ws layout (float offsets) ----
#define CORR_OFF 0u          // padded corr: [b][h][518][34]; halo handled in k3 stager
#define WQ_OFF   1127168u    // softmax weights [b][512][32]

// ---------------- K1: projections xm1 = W^T@X + b ----------------
// R12: k1 = R10/R6 verbatim (tied-best). k1 ledger closed: scalar(47us) /
// LDS-dbuf(-2.3) / DS-only-W(-7.9) / counted-vmcnt(+6) / VGPR-ring(0) /
// 2xTLP(+10) -- ILP, TLP, request count, barrier structure all falsified.
// Four independent structures pin at ~2.3TB/s effective for the 1KB-island
// @128KB-stride stream: pattern-level ceiling, not software.
__global__ __launch_bounds__(256) void k1_proj(const float* __restrict__ xm, const float* __restrict__ xf,
                                               const float* __restrict__ w1, const float* __restrict__ b1,
                                               const float* __restrict__ w2, const float* __restrict__ b2,
                                               float* __restrict__ xm1, float* __restrict__ xf1){
  int blk  = blockIdx.x;
  int mblk = blk & 127;
  int bt   = blk >> 7;           // 0..3
  int b    = bt >> 1, sel = bt & 1;
  int m0   = mblk * 256;
  int tid  = threadIdx.x;

  const float* X    = (sel ? xf : xm) + (size_t)b * (C_*T_*F_) + m0;
  const float* W    = sel ? w2 : w1;
  const float* bias = sel ? b2 : b1;

  __shared__ float wls[C_*H_];      // 16KB: full W [c][h]
#pragma unroll
  for (int i = 0; i < 4; i++)
    *(float4*)(wls + i*1024 + tid*4) = *(const float4*)(W + i*1024 + tid*4);

  int mg = tid & 63;             // m sub-tile: 4 consecutive floats
  int hg = tid >> 6;             // h sub-tile: 8 consecutive h (constant per wave)
  const float* Xm = X + (mg << 2);

  float4 acc[8];
#pragma unroll
  for (int j = 0; j < 8; j++) acc[j] = make_float4(0.f,0.f,0.f,0.f);

  // 8-deep prefetch ring (fully static indices after unroll -> stays in VGPRs)
  float4 buf[8];
#pragma unroll
  for (int i = 0; i < 8; i++)
    buf[i] = *(const float4*)(Xm + (size_t)i * (T_*F_));

  __syncthreads();               // W staged (the only barrier)

#define FMA4(A, Wv) do { \
    A.x = fmaf((Wv), xv.x, A.x); A.y = fmaf((Wv), xv.y, A.y); \
    A.z = fmaf((Wv), xv.z, A.z); A.w = fmaf((Wv), xv.w, A.w); } while (0)

#define K1_BODY(c_) do {                                                  \
    const float* wk = wls + (c_)*H_ + hg*8;                               \
    float4 wa = *(const float4*)(wk);                                     \
    float4 wb = *(const float4*)(wk + 4);                                 \
    FMA4(acc[0], wa.x); FMA4(acc[1], wa.y); FMA4(acc[2], wa.z); FMA4(acc[3], wa.w); \
    FMA4(acc[4], wb.x); FMA4(acc[5], wb.y); FMA4(acc[6], wb.z); FMA4(acc[7], wb.w); \
  } while (0)

  for (int cb = 0; cb < 15; cb++){
#pragma unroll
    for (int i = 0; i < 8; i++){
      float4 xv = buf[i];
      buf[i] = *(const float4*)(Xm + (size_t)(cb*8 + 8 + i) * (T_*F_));  // prefetch c+8
      K1_BODY(cb*8 + i);
    }
  }
#pragma unroll
  for (int i = 0; i < 8; i++){
    float4 xv = buf[i];
    K1_BODY(120 + i);
  }

  float* O = (sel ? xf1 : xm1) + (size_t)b * (H_*T_*F_) + m0 + (mg << 2);
#pragma unroll
  for (int j = 0; j < 8; j++){
    int h = hg*8 + j;
    float bv = bias[h];
    float4 o = make_float4(acc[j].x + bv, acc[j].y + bv, acc[j].z + bv, acc[j].w + bv);
    *(float4*)(O + (size_t)h * (T_*F_)) = o;
  }
#undef FMA4
#undef K1_BODY
}

// ---------------- K2: corr[b,h,t,d] = sum_f xm1[b,h,t,f] * xf1[b,h,t+d-31,f] ----------------
// R7: XOR-swizzle Bl (kept). R12: XCD-aware blk remap (T1) -- tt-adjacent
// blocks share a 31KB B-halo; launch round-robin put them on different XCDs.
// Remap blk = (L&7)*64 + L>>3 (bijective, 512%8==0): XCD x serves a
// contiguous blk chain -> halo hits local L2.
#define BSW(r) ((((r) >> 3) & 7) << 2)

__global__ __launch_bounds__(256) void k2_corr(const float* __restrict__ xm1, const float* __restrict__ xf1,
                                               float* __restrict__ corr_pad){
  int L = blockIdx.x;
  int blk = (L & 7) * 64 + (L >> 3);   // XCD swizzle
  int tt = blk & 7, h = (blk >> 3) & 31, b = blk >> 8;
  int t0 = tt * 64;
  const float* A  = xm1 + ((size_t)(b*H_ + h)) * (T_*F_);
  const float* Bm = xf1 + ((size_t)(b*H_ + h)) * (T_*F_);

  __shared__ float Al[64*68];
  __shared__ float Bl[95*68];
  int tid = threadIdx.x;

  for (int idx = tid; idx < 64*16; idx += 256){
    int r = idx >> 4, q = idx & 15;
    *(float4*)(Al + r*68 + q*4) = *(const float4*)(A + (size_t)(t0 + r)*F_ + q*4);
  }
  for (int idx = tid; idx < 95*16; idx += 256){
    int r = idx >> 4, q = idx & 15;
    int gr = t0 - 31 + r;
    float4 v = make_float4(0.f,0.f,0.f,0.f);
    if (gr >= 0) v = *(const float4*)(Bm + (size_t)gr*F_ + q*4);
    *(float4*)(Bl + r*68 + ((q*4) ^ BSW(r))) = v;
  }
  __syncthreads();

  int tl = tid >> 2, dg = tid & 3;
  float acc[8];
#pragma unroll
  for (int j = 0; j < 8; j++) acc[j] = 0.f;

  for (int fq = 0; fq < 16; fq++){
    float4 a = *(const float4*)(Al + tl*68 + fq*4);
#pragma unroll
    for (int j = 0; j < 8; j++){
      int rbj = tl + dg*8 + j;
      float4 bv = *(const float4*)(Bl + rbj*68 + ((fq*4) ^ BSW(rbj)));
      acc[j] += a.x*bv.x + a.y*bv.y + a.z*bv.z + a.w*bv.w;
    }
  }
  float* o = corr_pad + ((size_t)(b*H_ + h))*(518*34) + (size_t)(t0 + tl + 3)*34 + (dg*8 + 1);
#pragma unroll
  for (int j = 0; j < 8; j++) o[j] = acc[j];
}

// ---------------- K3: 5x3 conv over (t,d) summing h + bc, causal mask, softmax over d ----------------
__global__ __launch_bounds__(256) void k3_conv_softmax(const float* __restrict__ corr_pad,
                                                       const float* __restrict__ wc, const float* __restrict__ bc,
                                                       float* __restrict__ wq){
  int b  = blockIdx.x >> 6;
  int t0 = (blockIdx.x & 63) * 8;
  int tid = threadIdx.x;

  __shared__ float ls[32*12*34];   // [h][12 rows t0..t0+11][34 d]
  const float* cp = corr_pad + (size_t)b * (H_*518*34);
  for (int idx = tid; idx < 32*12*34; idx += 256){
    int h = idx / 408, rem = idx - h*408;
    int r = rem / 34, dd = rem - r*34;
    int gr = t0 + r;
    bool halo = (gr < 3) | (gr > 514) | (dd == 0) | (dd == 33);
    ls[idx] = halo ? 0.f : cp[(size_t)h*(518*34) + (size_t)gr*34 + dd];
  }
  __syncthreads();

  int tl = tid >> 5, d = tid & 31;
  int t = t0 + tl;

  float val = bc[0];
  for (int h = 0; h < H_; h++){
    const float* base = ls + h*408 + tl*34 + d;
    const float* wch = wc + h*15;
#pragma unroll
    for (int kh = 0; kh < 5; kh++){
#pragma unroll
      for (int kw = 0; kw < 3; kw++){
        val += base[kh*34 + kw] * wch[kh*3 + kw];
      }
    }
  }
  if (t + d < D_ - 1) val = -1e13f;

  float m = val;
#pragma unroll
  for (int off = 16; off > 0; off >>= 1) m = fmaxf(m, __shfl_xor(m, off));
  float e = __expf(val - m);
  float s = e;
#pragma unroll
  for (int off = 16; off > 0; off >>= 1) s += __shfl_xor(s, off);

  wq[((size_t)b*T_ + t)*D_ + d] = e / s;
}

// ---------------- K4: out[b,c,t,f] = sum_d w[b,t,d] * xf[b,c,t+d-31,f] ----------------
// R12: XCD-aware blk remap (T1). tt-adjacent blocks share a 31KB xf halo;
// remap blk = (L&7)*256 + L>>3 (bijective, 2048%8==0) puts each (b,c)'s 8
// tt-tiles on one XCD -> halo served from local L2 instead of L3.
__global__ __launch_bounds__(256) void k4_out(const float* __restrict__ xf, const float* __restrict__ wq,
                                              float* __restrict__ out){
  int L = blockIdx.x;
  int blk = (L & 7) * 256 + (L >> 3);  // XCD swizzle
  int tt = blk & 7, c = (blk >> 3) & 127, b = blk >> 10;
  int t0 = tt * 64;
  const float* Xf = xf + ((size_t)(b*C_ + c)) * (T_*F_);

  __shared__ float xfl[95*68];
  __shared__ float wl[64*33];
  int tid = threadIdx.x;

  for (int idx = tid; idx < 95*16; idx += 256){
    int r = idx >> 4, q = idx & 15;
    int gr = t0 - 31 + r;
    float4 v = make_float4(0.f,0.f,0.f,0.f);
    if (gr >= 0) v = *(const float4*)(Xf + (size_t)gr*F_ + q*4);
    *(float4*)(xfl + r*68 + q*4) = v;
  }
  for (int idx = tid; idx < 64*8; idx += 256){
    int r = idx >> 3, q = idx & 7;
    float4 v = *(const float4*)(wq + ((size_t)b*T_ + t0 + r)*D_ + q*4);
    wl[r*33 + q*4 + 0] = v.x; wl[r*33 + q*4 + 1] = v.y;
    wl[r*33 + q*4 + 2] = v.z; wl[r*33 + q*4 + 3] = v.w;
  }
  __syncthreads();

  int tg = tid >> 4, q = tid & 15;
  float4 acc[4];
#pragma unroll
  for (int j = 0; j < 4; j++) acc[j] = make_float4(0.f,0.f,0.f,0.f);

#pragma unroll
  for (int rr = 0; rr < 35; rr++){
    float4 xv = *(const float4*)(xfl + (tg*4 + rr)*68 + q*4);
#pragma unroll
    for (int j = 0; j < 4; j++){
      int d = rr - j;
      if (d >= 0 && d < D_){
        float wv = wl[(tg*4 + j)*33 + d];
        acc[j].x += wv * xv.x; acc[j].y += wv * xv.y;
        acc[j].z += wv * xv.z; acc[j].w += wv * xv.w;
      }
    }
  }
#pragma unroll
  for (int j = 0; j < 4; j++){
    int t = t0 + tg*4 + j;
    float* O = out + (((size_t)(b*C_ + c))*T_ + t)*F_ + q*4;
    *(float4*)O = acc[j];
  }
}

extern "C" void kernel_launch(void* const* d_in, const int* in_sizes, int n_in,
                              void* d_out, int out_size, void* d_ws, size_t ws_size,
                              hipStream_t stream) {
  const float* xm = (const float*)d_in[0];
  const float* xf = (const float*)d_in[1];
  const float* w1 = (const float*)d_in[2];
  const float* b1 = (const float*)d_in[3];
  const float* w2 = (const float*)d_in[4];
  const float* b2 = (const float*)d_in[5];
  const float* wc = (const float*)d_in[6];
  const float* bc = (const float*)d_in[7];
  float* ws = (float*)d_ws;

  float* xm1 = (float*)d_out + XM1_OUT;
  float* xf1 = (float*)d_out + XF1_OUT;

  hipLaunchKernelGGL(k1_proj, dim3(512), dim3(256), 0, stream, xm, xf, w1, b1, w2, b2, xm1, xf1);
  hipLaunchKernelGGL(k2_corr, dim3(512), dim3(256), 0, stream, xm1, xf1, ws + CORR_OFF);
  hipLaunchKernelGGL(k3_conv_softmax, dim3(128), dim3(256), 0, stream, ws + CORR_OFF, wc, bc, ws + WQ_OFF);
  hipLaunchKernelGGL(k4_out, dim3(2048), dim3(256), 0, stream, xf, ws + WQ_OFF, (float*)d_out);
}

// Round 9
// 172.215 us; speedup vs baseline: 1.0618x; 1.0285x over previous
//
#include <hip/hip_runtime.h>

typedef unsigned short u16;
typedef unsigned int   u32;

#define B_ 2
#define C_ 128
#define T_ 512
#define F_ 64
#define H_ 32
#define D_ 32

// ---- d_out scratch (float offsets): xm1/xf1 fp32 intermediates live in d_out ----
#define XM1_OUT 0u
#define XF1_OUT 2097152u

// ---- d_ws layout (float offsets) ----
#define CORR_OFF 0u          // padded corr: [b][h][518][34]; halo handled in k3 stager
#define WQ_OFF   1127168u    // softmax weights [b][512][32]

// ---------------- K1: projections xm1 = W^T@X + b ----------------
// R13 = exact revert to the R6 build (best measured: 172.74us).
// k1 ledger closed: scalar(47us) / LDS-dbuf(-2.3) / DS-only-W(-7.9) /
// counted-vmcnt(+6) / VGPR-ring(0) / 2xTLP(+10) / XCD-swizzle k2k4(+4.4).
// Four independent k1 structures pin at ~2.2-2.4 TB/s effective for the
// 1KB-island @128KB-stride stream: pattern-level ceiling, not software.
__global__ __launch_bounds__(256) void k1_proj(const float* __restrict__ xm, const float* __restrict__ xf,
                                               const float* __restrict__ w1, const float* __restrict__ b1,
                                               const float* __restrict__ w2, const float* __restrict__ b2,
                                               float* __restrict__ xm1, float* __restrict__ xf1){
  int blk  = blockIdx.x;
  int mblk = blk & 127;
  int bt   = blk >> 7;           // 0..3
  int b    = bt >> 1, sel = bt & 1;
  int m0   = mblk * 256;
  int tid  = threadIdx.x;

  const float* X    = (sel ? xf : xm) + (size_t)b * (C_*T_*F_) + m0;
  const float* W    = sel ? w2 : w1;
  const float* bias = sel ? b2 : b1;

  __shared__ float wls[C_*H_];      // 16KB: full W [c][h]
#pragma unroll
  for (int i = 0; i < 4; i++)
    *(float4*)(wls + i*1024 + tid*4) = *(const float4*)(W + i*1024 + tid*4);

  int mg = tid & 63;             // m sub-tile: 4 consecutive floats
  int hg = tid >> 6;             // h sub-tile: 8 consecutive h (constant per wave)
  const float* Xm = X + (mg << 2);

  float4 acc[8];
#pragma unroll
  for (int j = 0; j < 8; j++) acc[j] = make_float4(0.f,0.f,0.f,0.f);

  // 8-deep prefetch ring (fully static indices after unroll -> stays in VGPRs)
  float4 buf[8];
#pragma unroll
  for (int i = 0; i < 8; i++)
    buf[i] = *(const float4*)(Xm + (size_t)i * (T_*F_));

  __syncthreads();               // W staged (the only barrier)

#define FMA4(A, Wv) do { \
    A.x = fmaf((Wv), xv.x, A.x); A.y = fmaf((Wv), xv.y, A.y); \
    A.z = fmaf((Wv), xv.z, A.z); A.w = fmaf((Wv), xv.w, A.w); } while (0)

#define K1_BODY(c_) do {                                                  \
    const float* wk = wls + (c_)*H_ + hg*8;                               \
    float4 wa = *(const float4*)(wk);                                     \
    float4 wb = *(const float4*)(wk + 4);                                 \
    FMA4(acc[0], wa.x); FMA4(acc[1], wa.y); FMA4(acc[2], wa.z); FMA4(acc[3], wa.w); \
    FMA4(acc[4], wb.x); FMA4(acc[5], wb.y); FMA4(acc[6], wb.z); FMA4(acc[7], wb.w); \
  } while (0)

  for (int cb = 0; cb < 15; cb++){
#pragma unroll
    for (int i = 0; i < 8; i++){
      float4 xv = buf[i];
      buf[i] = *(const float4*)(Xm + (size_t)(cb*8 + 8 + i) * (T_*F_));  // prefetch c+8
      K1_BODY(cb*8 + i);
    }
  }
#pragma unroll
  for (int i = 0; i < 8; i++){
    float4 xv = buf[i];
    K1_BODY(120 + i);
  }

  float* O = (sel ? xf1 : xm1) + (size_t)b * (H_*T_*F_) + m0 + (mg << 2);
#pragma unroll
  for (int j = 0; j < 8; j++){
    int h = hg*8 + j;
    float bv = bias[h];
    float4 o = make_float4(acc[j].x + bv, acc[j].y + bv, acc[j].z + bv, acc[j].w + bv);
    *(float4*)(O + (size_t)h * (T_*F_)) = o;
  }
#undef FMA4
#undef K1_BODY
}

// ---------------- K2: corr[b,h,t,d] = sum_f xm1[b,h,t,f] * xf1[b,h,t+d-31,f] ----------------
// R7 bank swizzle kept: rows differing by 8 at stride 68 floats hit the same
// bank; swizzle float4 slot by ((r>>3)&7)<<2, same on write+read.
// R13: XCD remap REMOVED (R8: +4.4us regression -- halo is L3-resident; the
// remap destroyed default dispatch's sequential-address adjacency).
#define BSW(r) ((((r) >> 3) & 7) << 2)

__global__ __launch_bounds__(256) void k2_corr(const float* __restrict__ xm1, const float* __restrict__ xf1,
                                               float* __restrict__ corr_pad){
  int blk = blockIdx.x;
  int tt = blk & 7, h = (blk >> 3) & 31, b = blk >> 8;
  int t0 = tt * 64;
  const float* A  = xm1 + ((size_t)(b*H_ + h)) * (T_*F_);
  const float* Bm = xf1 + ((size_t)(b*H_ + h)) * (T_*F_);

  __shared__ float Al[64*68];
  __shared__ float Bl[95*68];
  int tid = threadIdx.x;

  for (int idx = tid; idx < 64*16; idx += 256){
    int r = idx >> 4, q = idx & 15;
    *(float4*)(Al + r*68 + q*4) = *(const float4*)(A + (size_t)(t0 + r)*F_ + q*4);
  }
  for (int idx = tid; idx < 95*16; idx += 256){
    int r = idx >> 4, q = idx & 15;
    int gr = t0 - 31 + r;
    float4 v = make_float4(0.f,0.f,0.f,0.f);
    if (gr >= 0) v = *(const float4*)(Bm + (size_t)gr*F_ + q*4);
    *(float4*)(Bl + r*68 + ((q*4) ^ BSW(r))) = v;
  }
  __syncthreads();

  int tl = tid >> 2, dg = tid & 3;
  float acc[8];
#pragma unroll
  for (int j = 0; j < 8; j++) acc[j] = 0.f;

  for (int fq = 0; fq < 16; fq++){
    float4 a = *(const float4*)(Al + tl*68 + fq*4);
#pragma unroll
    for (int j = 0; j < 8; j++){
      int rbj = tl + dg*8 + j;
      float4 bv = *(const float4*)(Bl + rbj*68 + ((fq*4) ^ BSW(rbj)));
      acc[j] += a.x*bv.x + a.y*bv.y + a.z*bv.z + a.w*bv.w;
    }
  }
  float* o = corr_pad + ((size_t)(b*H_ + h))*(518*34) + (size_t)(t0 + tl + 3)*34 + (dg*8 + 1);
#pragma unroll
  for (int j = 0; j < 8; j++) o[j] = acc[j];
}

// ---------------- K3: 5x3 conv over (t,d) summing h + bc, causal mask, softmax over d ----------------
__global__ __launch_bounds__(256) void k3_conv_softmax(const float* __restrict__ corr_pad,
                                                       const float* __restrict__ wc, const float* __restrict__ bc,
                                                       float* __restrict__ wq){
  int b  = blockIdx.x >> 6;
  int t0 = (blockIdx.x & 63) * 8;
  int tid = threadIdx.x;

  __shared__ float ls[32*12*34];   // [h][12 rows t0..t0+11][34 d]
  const float* cp = corr_pad + (size_t)b * (H_*518*34);
  for (int idx = tid; idx < 32*12*34; idx += 256){
    int h = idx / 408, rem = idx - h*408;
    int r = rem / 34, dd = rem - r*34;
    int gr = t0 + r;
    bool halo = (gr < 3) | (gr > 514) | (dd == 0) | (dd == 33);
    ls[idx] = halo ? 0.f : cp[(size_t)h*(518*34) + (size_t)gr*34 + dd];
  }
  __syncthreads();

  int tl = tid >> 5, d = tid & 31;
  int t = t0 + tl;

  float val = bc[0];
  for (int h = 0; h < H_; h++){
    const float* base = ls + h*408 + tl*34 + d;
    const float* wch = wc + h*15;
#pragma unroll
    for (int kh = 0; kh < 5; kh++){
#pragma unroll
      for (int kw = 0; kw < 3; kw++){
        val += base[kh*34 + kw] * wch[kh*3 + kw];
      }
    }
  }
  if (t + d < D_ - 1) val = -1e13f;

  float m = val;
#pragma unroll
  for (int off = 16; off > 0; off >>= 1) m = fmaxf(m, __shfl_xor(m, off));
  float e = __expf(val - m);
  float s = e;
#pragma unroll
  for (int off = 16; off > 0; off >>= 1) s += __shfl_xor(s, off);

  wq[((size_t)b*T_ + t)*D_ + d] = e / s;
}

// ---------------- K4: out[b,c,t,f] = sum_d w[b,t,d] * xf[b,c,t+d-31,f] ----------------
// R13: XCD remap removed (R8 regression).
__global__ __launch_bounds__(256) void k4_out(const float* __restrict__ xf, const float* __restrict__ wq,
                                              float* __restrict__ out){
  int blk = blockIdx.x;
  int tt = blk & 7, c = (blk >> 3) & 127, b = blk >> 10;
  int t0 = tt * 64;
  const float* Xf = xf + ((size_t)(b*C_ + c)) * (T_*F_);

  __shared__ float xfl[95*68];
  __shared__ float wl[64*33];
  int tid = threadIdx.x;

  for (int idx = tid; idx < 95*16; idx += 256){
    int r = idx >> 4, q = idx & 15;
    int gr = t0 - 31 + r;
    float4 v = make_float4(0.f,0.f,0.f,0.f);
    if (gr >= 0) v = *(const float4*)(Xf + (size_t)gr*F_ + q*4);
    *(float4*)(xfl + r*68 + q*4) = v;
  }
  for (int idx = tid; idx < 64*8; idx += 256){
    int r = idx >> 3, q = idx & 7;
    float4 v = *(const float4*)(wq + ((size_t)b*T_ + t0 + r)*D_ + q*4);
    wl[r*33 + q*4 + 0] = v.x; wl[r*33 + q*4 + 1] = v.y;
    wl[r*33 + q*4 + 2] = v.z; wl[r*33 + q*4 + 3] = v.w;
  }
  __syncthreads();

  int tg = tid >> 4, q = tid & 15;
  float4 acc[4];
#pragma unroll
  for (int j = 0; j < 4; j++) acc[j] = make_float4(0.f,0.f,0.f,0.f);

#pragma unroll
  for (int rr = 0; rr < 35; rr++){
    float4 xv = *(const float4*)(xfl + (tg*4 + rr)*68 + q*4);
#pragma unroll
    for (int j = 0; j < 4; j++){
      int d = rr - j;
      if (d >= 0 && d < D_){
        float wv = wl[(tg*4 + j)*33 + d];
        acc[j].x += wv * xv.x; acc[j].y += wv * xv.y;
        acc[j].z += wv * xv.z; acc[j].w += wv * xv.w;
      }
    }
  }
#pragma unroll
  for (int j = 0; j < 4; j++){
    int t = t0 + tg*4 + j;
    float* O = out + (((size_t)(b*C_ + c))*T_ + t)*F_ + q*4;
    *(float4*)O = acc[j];
  }
}

extern "C" void kernel_launch(void* const* d_in, const int* in_sizes, int n_in,
                              void* d_out, int out_size, void* d_ws, size_t ws_size,
                              hipStream_t stream) {
  const float* xm = (const float*)d_in[0];
  const float* xf = (const float*)d_in[1];
  const float* w1 = (const float*)d_in[2];
  const float* b1 = (const float*)d_in[3];
  const float* w2 = (const float*)d_in[4];
  const float* b2 = (const float*)d_in[5];
  const float* wc = (const float*)d_in[6];
  const float* bc = (const float*)d_in[7];
  float* ws = (float*)d_ws;

  float* xm1 = (float*)d_out + XM1_OUT;
  float* xf1 = (float*)d_out + XF1_OUT;

  hipLaunchKernelGGL(k1_proj, dim3(512), dim3(256), 0, stream, xm, xf, w1, b1, w2, b2, xm1, xf1);
  hipLaunchKernelGGL(k2_corr, dim3(512), dim3(256), 0, stream, xm1, xf1, ws + CORR_OFF);
  hipLaunchKernelGGL(k3_conv_softmax, dim3(128), dim3(256), 0, stream, ws + CORR_OFF, wc, bc, ws + WQ_OFF);
  hipLaunchKernelGGL(k4_out, dim3(2048), dim3(256), 0, stream, xf, ws + WQ_OFF, (float*)d_out);
}